// Round 1
// baseline (4176.751 us; speedup 1.0000x reference)
//
#include <hip/hip_runtime.h>
#include <math.h>

#define NB 8
#define NC 24
#define NA 96
#define NW 96
#define NF 32
#define NHID 128
#define AW (NA*NW)           // 9216
#define NBC (NB*NC)          // 192
#define NEL ((size_t)NBC*AW) // 1769472

// ---------------------------------------------------------------- stats
__global__ __launch_bounds__(256) void stats_kernel(
    const float* __restrict__ x, const int* __restrict__ rows_len,
    const int* __restrict__ cols_len, float* __restrict__ stats)
{
    int bc = blockIdx.x;
    int R = rows_len[bc], L = cols_len[bc];
    const float* xp = x + (size_t)bc * AW;
    int n = R * L;
    float sx = 0.f, sxx = 0.f;
    for (int i = threadIdx.x; i < n; i += 256) {
        int a = i / L, w = i - a * L;
        float v = xp[a * NW + w];
        sx += v;
        sxx = fmaf(v, v, sxx);
    }
    __shared__ float r1[256], r2[256];
    r1[threadIdx.x] = sx; r2[threadIdx.x] = sxx;
    __syncthreads();
    for (int s = 128; s > 0; s >>= 1) {
        if (threadIdx.x < s) {
            r1[threadIdx.x] += r1[threadIdx.x + s];
            r2[threadIdx.x] += r2[threadIdx.x + s];
        }
        __syncthreads();
    }
    if (threadIdx.x == 0) {
        float fn = (float)n;
        float mean = r1[0] / fn;
        float var = fmaxf((r2[0] - r1[0] * r1[0] / fn) / (fn - 1.f), 0.f);
        float sd = fmaxf(sqrtf(var), 1e-12f);
        stats[2 * bc] = mean;
        stats[2 * bc + 1] = 1.f / sd;
    }
}

// ---------------------------------------------------------------- t0 MLP (1->128->32), writes planar h
__global__ __launch_bounds__(256) void t0_kernel(
    const float* __restrict__ x, const int* __restrict__ rows_len,
    const int* __restrict__ cols_len, const float* __restrict__ stats,
    const float* __restrict__ w1, const float* __restrict__ b1,
    const float* __restrict__ w2, const float* __restrict__ b2,
    float* __restrict__ h)
{
    __shared__ __align__(16) float sw2[NHID * NF];
    __shared__ float sw1[NHID], sb1v[NHID], sb2v[NF];
    int tid = threadIdx.x;
    for (int i = tid; i < NHID * NF; i += 256) sw2[i] = w2[i];
    if (tid < NHID) { sw1[tid] = w1[tid]; sb1v[tid] = b1[tid]; }
    if (tid < NF) sb2v[tid] = b2[tid];
    __syncthreads();

    int bc = blockIdx.x / 18;
    int base = (blockIdx.x % 18) * 512;
    int R = rows_len[bc], L = cols_len[bc];
    float mean = stats[2 * bc], rstd = stats[2 * bc + 1];

    int eA = base + tid, eB = eA + 256;
    int aA = eA / NW, wA = eA % NW;
    int aB = eB / NW, wB = eB % NW;
    bool vA = (aA < R) && (wA < L);
    bool vB = (aB < R) && (wB < L);
    size_t gA = (size_t)bc * AW + eA;
    float xA = vA ? (x[gA] - mean) * rstd : 0.f;
    float xB = vB ? (x[gA + 256] - mean) * rstd : 0.f;

    float oA[NF], oB[NF];
    #pragma unroll
    for (int f = 0; f < NF; f++) { oA[f] = sb2v[f]; oB[f] = sb2v[f]; }
    for (int j = 0; j < NHID; j++) {
        float hA = fmaxf(fmaf(xA, sw1[j], sb1v[j]), 0.f);
        float hB = fmaxf(fmaf(xB, sw1[j], sb1v[j]), 0.f);
        const float4* wr = (const float4*)&sw2[j * NF];
        #pragma unroll
        for (int f4 = 0; f4 < 8; f4++) {
            float4 q = wr[f4];
            oA[4*f4+0] = fmaf(hA, q.x, oA[4*f4+0]); oB[4*f4+0] = fmaf(hB, q.x, oB[4*f4+0]);
            oA[4*f4+1] = fmaf(hA, q.y, oA[4*f4+1]); oB[4*f4+1] = fmaf(hB, q.y, oB[4*f4+1]);
            oA[4*f4+2] = fmaf(hA, q.z, oA[4*f4+2]); oB[4*f4+2] = fmaf(hB, q.z, oB[4*f4+2]);
            oA[4*f4+3] = fmaf(hA, q.w, oA[4*f4+3]); oB[4*f4+3] = fmaf(hB, q.w, oB[4*f4+3]);
        }
    }
    float mA = vA ? 1.f : 0.f, mB = vB ? 1.f : 0.f;
    float* hp = h + (size_t)bc * NF * AW;
    #pragma unroll
    for (int f = 0; f < NF; f++) {
        hp[(size_t)f * AW + eA] = oA[f] * mA;
        hp[(size_t)f * AW + eB] = oB[f] * mB;
    }
}

// ---------------------------------------------------------------- pools: row/col/mat sin-sums + channel max
__global__ __launch_bounds__(256) void pool_kernel(
    const float* __restrict__ h, float* __restrict__ rowsum,
    float* __restrict__ colsum, float* __restrict__ matsum,
    float* __restrict__ cmax)
{
    int bc = blockIdx.x;
    const float* basep = h + (size_t)bc * NF * AW;
    int tid = threadIdx.x;

    // row sums of sin(ch 4k+1): tasks k*NA + a
    for (int task = tid; task < 8 * NA; task += 256) {
        int k = task / NA, a = task - k * NA;
        const float* p = basep + (size_t)(4 * k + 1) * AW + a * NW;
        float s = 0.f;
        for (int w = 0; w < NW; w++) s += sinf(p[w]);
        rowsum[(bc * NA + a) * 8 + k] = s;
    }
    // col sums of sin(ch 4k+2)
    for (int task = tid; task < 8 * NW; task += 256) {
        int k = task / NW, w = task - k * NW;
        const float* p = basep + (size_t)(4 * k + 2) * AW + w;
        float s = 0.f;
        for (int a = 0; a < NA; a++) s += sinf(p[a * NW]);
        colsum[(bc * NW + w) * 8 + k] = s;
    }
    // matrix sums of sin(ch 4k+3)
    {
        int k = tid >> 5, ti = tid & 31;
        const float* p = basep + (size_t)(4 * k + 3) * AW;
        float s = 0.f;
        for (int i = ti; i < AW; i += 32) s += sinf(p[i]);
        #pragma unroll
        for (int off = 16; off >= 1; off >>= 1) s += __shfl_xor(s, off, 64);
        if (ti == 0) matsum[bc * 8 + k] = s;
    }
    // per-(bc, channel) max of h (h already masked; zeros included, matching ref)
    {
        int f = tid >> 3, g = tid & 7;
        const float* p = basep + (size_t)f * AW;
        float mx = -3.402823466e38f;
        for (int i = g; i < AW; i += 8) mx = fmaxf(mx, p[i]);
        __shared__ float red[NF][9];
        red[f][g] = mx;
        __syncthreads();
        if (tid < NF) {
            float m = red[tid][0];
            #pragma unroll
            for (int g2 = 1; g2 < 8; g2++) m = fmaxf(m, red[tid][g2]);
            cmax[bc * NF + tid] = m;
        }
    }
}

// ---------------------------------------------------------------- stack MLP (residual), 2 elements/thread
__global__ __launch_bounds__(256, 2) void mlp_kernel(
    float* __restrict__ h, const float* __restrict__ rowsum,
    const float* __restrict__ colsum, const float* __restrict__ matsum,
    const float* __restrict__ cmax, const int* __restrict__ rows_len,
    const int* __restrict__ cols_len, const float* __restrict__ w1,
    const float* __restrict__ b1, const float* __restrict__ w2,
    const float* __restrict__ b2)
{
    __shared__ __align__(16) float sW1T[NHID * 24];  // [j][t], t = e0/e1/e2 rows 0..23
    __shared__ __align__(16) float sW2[NHID * NF];   // [j][f]
    __shared__ float sconst[NHID];
    __shared__ float sb2v[NF];
    __shared__ float sbm[NF];
    int tid = threadIdx.x;
    int bc = blockIdx.x / 18;
    int b = bc / NC;

    for (int i = tid; i < NHID * 24; i += 256) {
        int j = i / 24, t = i - j * 24;
        sW1T[i] = w1[t * NHID + j];
    }
    for (int i = tid; i < NHID * NF; i += 256) sW2[i] = w2[i];
    if (tid < NF) sb2v[tid] = b2[tid];
    if (tid >= 224) {   // 32 threads: per-batch max over C
        int f = tid - 224;
        float m = cmax[(b * NC) * NF + f];
        for (int c = 1; c < NC; c++) m = fmaxf(m, cmax[(b * NC + c) * NF + f]);
        sbm[f] = m;
    }
    __syncthreads();
    if (tid < NHID) {   // fold b1 + e3 (matsum) + h1 (batch max) into per-block const
        int j = tid;
        float v = b1[j];
        const float* mp = matsum + bc * 8;
        #pragma unroll
        for (int k = 0; k < 8; k++) v = fmaf(mp[k], w1[(24 + k) * NHID + j], v);
        #pragma unroll
        for (int f = 0; f < NF; f++) v = fmaf(sbm[f], w1[(32 + f) * NHID + j], v);
        sconst[j] = v;
    }
    __syncthreads();

    int R = rows_len[bc], L = cols_len[bc];
    int base = (blockIdx.x % 18) * 512;
    int eA = base + tid, eB = eA + 256;
    int aA = eA / NW, wA = eA % NW;
    int aB = eB / NW, wB = eB % NW;
    float mkA = (aA < R && wA < L) ? 1.f : 0.f;
    float mkB = (aB < R && wB < L) ? 1.f : 0.f;

    float* hp = h + (size_t)bc * NF * AW;
    float hvA[NF], hvB[NF];
    #pragma unroll
    for (int f = 0; f < NF; f++) {
        hvA[f] = hp[(size_t)f * AW + eA];
        hvB[f] = hp[(size_t)f * AW + eB];
    }
    float pA[24], pB[24];
    #pragma unroll
    for (int k = 0; k < 8; k++) {
        pA[k] = sinf(hvA[4 * k]);   // e0: sin(ch 4k); zero at masked (hv==0)
        pB[k] = sinf(hvB[4 * k]);
    }
    {
        const float* rpA = rowsum + (bc * NA + aA) * 8;
        const float* rpB = rowsum + (bc * NA + aB) * 8;
        const float* cpA = colsum + (bc * NW + wA) * 8;
        const float* cpB = colsum + (bc * NW + wB) * 8;
        #pragma unroll
        for (int k = 0; k < 8; k++) {
            pA[8 + k]  = rpA[k]; pB[8 + k]  = rpB[k];
            pA[16 + k] = cpA[k]; pB[16 + k] = cpB[k];
        }
    }
    float oA[NF], oB[NF];
    #pragma unroll
    for (int f = 0; f < NF; f++) { oA[f] = sb2v[f]; oB[f] = sb2v[f]; }
    for (int j = 0; j < NHID; j++) {
        float vA = sconst[j], vB = sconst[j];
        const float4* wr = (const float4*)&sW1T[j * 24];
        #pragma unroll
        for (int t4 = 0; t4 < 6; t4++) {
            float4 q = wr[t4];
            vA = fmaf(pA[4*t4+0], q.x, vA); vB = fmaf(pB[4*t4+0], q.x, vB);
            vA = fmaf(pA[4*t4+1], q.y, vA); vB = fmaf(pB[4*t4+1], q.y, vB);
            vA = fmaf(pA[4*t4+2], q.z, vA); vB = fmaf(pB[4*t4+2], q.z, vB);
            vA = fmaf(pA[4*t4+3], q.w, vA); vB = fmaf(pB[4*t4+3], q.w, vB);
        }
        vA = fmaxf(vA, 0.f); vB = fmaxf(vB, 0.f);
        const float4* w2r = (const float4*)&sW2[j * NF];
        #pragma unroll
        for (int f4 = 0; f4 < 8; f4++) {
            float4 q = w2r[f4];
            oA[4*f4+0] = fmaf(vA, q.x, oA[4*f4+0]); oB[4*f4+0] = fmaf(vB, q.x, oB[4*f4+0]);
            oA[4*f4+1] = fmaf(vA, q.y, oA[4*f4+1]); oB[4*f4+1] = fmaf(vB, q.y, oB[4*f4+1]);
            oA[4*f4+2] = fmaf(vA, q.z, oA[4*f4+2]); oB[4*f4+2] = fmaf(vB, q.z, oB[4*f4+2]);
            oA[4*f4+3] = fmaf(vA, q.w, oA[4*f4+3]); oB[4*f4+3] = fmaf(vB, q.w, oB[4*f4+3]);
        }
    }
    #pragma unroll
    for (int f = 0; f < NF; f++) {
        hp[(size_t)f * AW + eA] = (hvA[f] + oA[f]) * mkA;
        hp[(size_t)f * AW + eB] = (hvB[f] + oB[f]) * mkB;
    }
}

// ---------------------------------------------------------------- RMS over (a,w)
__global__ __launch_bounds__(256) void rms_kernel(
    const float* __restrict__ h, const int* __restrict__ rows_len,
    const int* __restrict__ cols_len, float* __restrict__ rms)
{
    int bc = blockIdx.x;
    int f = threadIdx.x >> 3, g = threadIdx.x & 7;
    const float* p = h + ((size_t)bc * NF + f) * AW;
    float s = 0.f;
    for (int i = g; i < AW; i += 8) { float v = p[i]; s = fmaf(v, v, s); }
    __shared__ float red[NF][9];
    red[f][g] = s;
    __syncthreads();
    if (threadIdx.x < NF) {
        float t = 0.f;
        #pragma unroll
        for (int g2 = 0; g2 < 8; g2++) t += red[threadIdx.x][g2];
        float n = (float)(rows_len[bc] * cols_len[bc]);
        t = fmaxf(t, 1e-20f);
        rms[bc * NF + threadIdx.x] = sqrtf(t / fmaxf(n, 1e-12f));
    }
}

// ---------------------------------------------------------------- final mean-over-C + MLP + tanh
__global__ __launch_bounds__(64) void out_kernel(
    const float* __restrict__ rms, const float* __restrict__ w1,
    const float* __restrict__ b1, const float* __restrict__ w2,
    const float* __restrict__ b2, float* __restrict__ out)
{
    int b = threadIdx.x;
    if (b >= NB) return;
    float hm[NF];
    #pragma unroll
    for (int f = 0; f < NF; f++) {
        float s = 0.f;
        for (int c = 0; c < NC; c++) s += rms[(b * NC + c) * NF + f];
        hm[f] = s / (float)NC;
    }
    float o0 = b2[0], o1 = b2[1];
    for (int j = 0; j < NHID; j++) {
        float v = b1[j];
        #pragma unroll
        for (int f = 0; f < NF; f++) v = fmaf(hm[f], w1[f * NHID + j], v);
        v = fmaxf(v, 0.f);
        o0 = fmaf(v, w2[j * 2 + 0], o0);
        o1 = fmaf(v, w2[j * 2 + 1], o1);
    }
    out[b * 2 + 0] = 8.f * tanhf(o0);
    out[b * 2 + 1] = 8.f * tanhf(o1);
}

// ---------------------------------------------------------------- launcher
extern "C" void kernel_launch(void* const* d_in, const int* in_sizes, int n_in,
                              void* d_out, int out_size, void* d_ws, size_t ws_size,
                              hipStream_t stream)
{
    const float* x    = (const float*)d_in[0];
    const int* rl     = (const int*)d_in[1];
    const int* cl     = (const int*)d_in[2];
    const float* t0w1 = (const float*)d_in[3];
    const float* t0b1 = (const float*)d_in[4];
    const float* t0w2 = (const float*)d_in[5];
    const float* t0b2 = (const float*)d_in[6];
    const float* tw1  = (const float*)d_in[7];
    const float* tb1  = (const float*)d_in[8];
    const float* tw2  = (const float*)d_in[9];
    const float* tb2  = (const float*)d_in[10];
    const float* ow1  = (const float*)d_in[11];
    const float* ob1  = (const float*)d_in[12];
    const float* ow2  = (const float*)d_in[13];
    const float* ob2  = (const float*)d_in[14];
    float* out = (float*)d_out;

    float* ws    = (float*)d_ws;
    float* h     = ws;                               // NEL*NF  (planar [bc][f][a*96+w])
    float* stats = h + NEL * NF;                     // 2*NBC
    float* rowb  = stats + 2 * NBC;                  // NBC*NA*8
    float* colb  = rowb + (size_t)NBC * NA * 8;      // NBC*NW*8
    float* matb  = colb + (size_t)NBC * NW * 8;      // NBC*8
    float* cmxb  = matb + NBC * 8;                   // NBC*NF
    float* rmsb  = cmxb + NBC * NF;                  // NBC*NF

    stats_kernel<<<NBC, 256, 0, stream>>>(x, rl, cl, stats);
    t0_kernel<<<(int)(NEL / 512), 256, 0, stream>>>(x, rl, cl, stats,
                                                    t0w1, t0b1, t0w2, t0b2, h);
    for (int s = 0; s < 4; s++) {
        pool_kernel<<<NBC, 256, 0, stream>>>(h, rowb, colb, matb, cmxb);
        mlp_kernel<<<NBC * 18, 256, 0, stream>>>(h, rowb, colb, matb, cmxb, rl, cl,
            tw1 + (size_t)s * 64 * NHID, tb1 + s * NHID,
            tw2 + (size_t)s * NHID * NF, tb2 + s * NF);
    }
    rms_kernel<<<NBC, 256, 0, stream>>>(h, rl, cl, rmsb);
    out_kernel<<<1, 64, 0, stream>>>(rmsb, ow1, ob1, ow2, ob2, out);
}

// Round 2
// 2091.468 us; speedup vs baseline: 1.9970x; 1.9970x over previous
//
#include <hip/hip_runtime.h>
#include <math.h>
#include <float.h>

#define NB 8
#define NC 24
#define NA 96
#define NW 96
#define NF 32
#define NHID 128
#define AW (NA*NW)           // 9216
#define NBC (NB*NC)          // 192
#define NEL ((size_t)NBC*AW) // 1769472

// ---------------------------------------------------------------- stats
__global__ __launch_bounds__(256) void stats_kernel(
    const float* __restrict__ x, const int* __restrict__ rows_len,
    const int* __restrict__ cols_len, float* __restrict__ stats)
{
    int bc = blockIdx.x;
    int R = rows_len[bc], L = cols_len[bc];
    const float* xp = x + (size_t)bc * AW;
    int n = R * L;
    float sx = 0.f, sxx = 0.f;
    for (int i = threadIdx.x; i < n; i += 256) {
        int a = i / L, w = i - a * L;
        float v = xp[a * NW + w];
        sx += v;
        sxx = fmaf(v, v, sxx);
    }
    __shared__ float r1[256], r2[256];
    r1[threadIdx.x] = sx; r2[threadIdx.x] = sxx;
    __syncthreads();
    for (int s = 128; s > 0; s >>= 1) {
        if (threadIdx.x < s) {
            r1[threadIdx.x] += r1[threadIdx.x + s];
            r2[threadIdx.x] += r2[threadIdx.x + s];
        }
        __syncthreads();
    }
    if (threadIdx.x == 0) {
        float fn = (float)n;
        float mean = r1[0] / fn;
        float var = fmaxf((r2[0] - r1[0] * r1[0] / fn) / (fn - 1.f), 0.f);
        float sd = fmaxf(sqrtf(var), 1e-12f);
        stats[2 * bc] = mean;
        stats[2 * bc + 1] = 1.f / sd;
    }
}

// ---------------------------------------------------------------- prep: transpose first 24 rows of each stack's W1
__global__ __launch_bounds__(256) void prep_kernel(
    const float* __restrict__ tw1, float* __restrict__ w1t)
{
    int i = blockIdx.x * 256 + threadIdx.x;     // [s][j][t]
    if (i >= 4 * NHID * 24) return;
    int s = i / (NHID * 24), r = i % (NHID * 24);
    int j = r / 24, t = r % 24;
    w1t[i] = tw1[(size_t)s * 64 * NHID + t * NHID + j];
}

// ---------------------------------------------------------------- t0 MLP (1->128->32), writes planar h
__global__ __launch_bounds__(256) void t0_kernel(
    const float* __restrict__ x, const int* __restrict__ rows_len,
    const int* __restrict__ cols_len, const float* __restrict__ stats,
    const float* __restrict__ w1, const float* __restrict__ b1,
    const float* __restrict__ w2, const float* __restrict__ b2,
    float* __restrict__ h)
{
    int tid = threadIdx.x;
    int bc = blockIdx.x / 18;
    int base = (blockIdx.x % 18) * 512;
    int R = rows_len[bc], L = cols_len[bc];
    float mean = stats[2 * bc], rstd = stats[2 * bc + 1];

    int eA = base + tid, eB = eA + 256;
    int aA = eA / NW, wA = eA % NW;
    int aB = eB / NW, wB = eB % NW;
    bool vA = (aA < R) && (wA < L);
    bool vB = (aB < R) && (wB < L);
    size_t gA = (size_t)bc * AW + eA;
    float xA = vA ? (x[gA] - mean) * rstd : 0.f;
    float xB = vB ? (x[gA + 256] - mean) * rstd : 0.f;

    float oA[NF], oB[NF];
    #pragma unroll
    for (int f = 0; f < NF; f++) { float bb = b2[f]; oA[f] = bb; oB[f] = bb; }
    for (int j = 0; j < NHID; j++) {
        float hA = fmaxf(fmaf(xA, w1[j], b1[j]), 0.f);
        float hB = fmaxf(fmaf(xB, w1[j], b1[j]), 0.f);
        const float* wr = &w2[j * NF];
        #pragma unroll
        for (int f = 0; f < NF; f++) {
            float q = wr[f];
            oA[f] = fmaf(hA, q, oA[f]);
            oB[f] = fmaf(hB, q, oB[f]);
        }
    }
    float mA = vA ? 1.f : 0.f, mB = vB ? 1.f : 0.f;
    float* hp = h + (size_t)bc * NF * AW;
    #pragma unroll
    for (int f = 0; f < NF; f++) {
        hp[(size_t)f * AW + eA] = oA[f] * mA;
        hp[(size_t)f * AW + eB] = oB[f] * mB;
    }
}

// ---------------------------------------------------------------- pools v2: one block per (bc, f) plane
__global__ __launch_bounds__(256) void pool_kernel(
    const float* __restrict__ h, float* __restrict__ rowsum,
    float* __restrict__ colsum, float* __restrict__ matsum,
    float* __restrict__ cmax)
{
    __shared__ float sred[4];
    __shared__ float scol[4][96];
    int blk = blockIdx.x;            // bc*32 + f
    int bc = blk >> 5, f = blk & 31;
    const float* p = h + (size_t)blk * AW;
    int tid = threadIdx.x;
    int lane = tid & 63, wv = tid >> 6;

    // ---- max over plane (coalesced strided pass)
    float mx = -FLT_MAX;
    for (int i = tid; i < AW; i += 256) mx = fmaxf(mx, p[i]);
    #pragma unroll
    for (int off = 32; off >= 1; off >>= 1) mx = fmaxf(mx, __shfl_xor(mx, off, 64));
    if (lane == 0) sred[wv] = mx;
    __syncthreads();
    if (tid == 0)
        cmax[bc * NF + f] = fmaxf(fmaxf(sred[0], sred[1]), fmaxf(sred[2], sred[3]));

    int mode = f & 3, k = f >> 2;
    if (mode == 1) {
        // row sums of sin: wave per row (rows wv, wv+4, ...)
        for (int r = 0; r < 24; r++) {
            int a = wv + 4 * r;
            float v1 = p[a * NW + lane];
            float s = sinf(v1);
            if (lane < 32) s += sinf(p[a * NW + 64 + lane]);
            #pragma unroll
            for (int off = 32; off >= 1; off >>= 1) s += __shfl_xor(s, off, 64);
            if (lane == 0) rowsum[(bc * NA + a) * 8 + k] = s;
        }
    } else if (mode == 2) {
        // col sums of sin: lane l accumulates col l (and 64+l for l<32)
        float acc0 = 0.f, acc1 = 0.f;
        for (int r = 0; r < 24; r++) {
            int a = wv + 4 * r;
            acc0 += sinf(p[a * NW + lane]);
            if (lane < 32) acc1 += sinf(p[a * NW + 64 + lane]);
        }
        scol[wv][lane] = acc0;
        if (lane < 32) scol[wv][64 + lane] = acc1;
        __syncthreads();
        if (tid < 96)
            colsum[(bc * NW + tid) * 8 + k] =
                scol[0][tid] + scol[1][tid] + scol[2][tid] + scol[3][tid];
    } else if (mode == 3) {
        // matrix sum of sin
        float s = 0.f;
        for (int i = tid; i < AW; i += 256) s += sinf(p[i]);
        #pragma unroll
        for (int off = 32; off >= 1; off >>= 1) s += __shfl_xor(s, off, 64);
        __syncthreads();
        if (lane == 0) sred[wv] = s;
        __syncthreads();
        if (tid == 0) matsum[bc * 8 + k] = sred[0] + sred[1] + sred[2] + sred[3];
    }
}

// ---------------------------------------------------------------- stack MLP v2: SGPR weights, 2 elem/thread
__global__ __launch_bounds__(256, 2) void mlp_kernel(
    float* __restrict__ h, const float* __restrict__ rowsum,
    const float* __restrict__ colsum, const float* __restrict__ matsum,
    const float* __restrict__ cmax, const int* __restrict__ rows_len,
    const int* __restrict__ cols_len, const float* __restrict__ w1t,
    const float* __restrict__ w1, const float* __restrict__ b1,
    const float* __restrict__ w2, const float* __restrict__ b2)
{
    __shared__ float sconst[NHID];
    __shared__ float sbm[NF];
    int tid = threadIdx.x;
    int bc = blockIdx.x / 18;
    int b = bc / NC;

    if (tid >= 224) {   // 32 threads: per-batch max over C
        int f = tid - 224;
        float m = cmax[(b * NC) * NF + f];
        for (int c = 1; c < NC; c++) m = fmaxf(m, cmax[(b * NC + c) * NF + f]);
        sbm[f] = m;
    }
    __syncthreads();
    if (tid < NHID) {   // fold b1 + e3 (matsum) + h1 (batch max) into per-block const
        int j = tid;
        float v = b1[j];
        const float* mp = matsum + bc * 8;
        #pragma unroll
        for (int k = 0; k < 8; k++) v = fmaf(mp[k], w1[(24 + k) * NHID + j], v);
        #pragma unroll
        for (int f = 0; f < NF; f++) v = fmaf(sbm[f], w1[(32 + f) * NHID + j], v);
        sconst[j] = v;
    }
    __syncthreads();

    int R = rows_len[bc], L = cols_len[bc];
    int base = (blockIdx.x % 18) * 512;
    int eA = base + tid, eB = eA + 256;
    int aA = eA / NW, wA = eA % NW;
    int aB = eB / NW, wB = eB % NW;
    float mkA = (aA < R && wA < L) ? 1.f : 0.f;
    float mkB = (aB < R && wB < L) ? 1.f : 0.f;

    float* hp = h + (size_t)bc * NF * AW;
    float pA[24], pB[24];
    #pragma unroll
    for (int k = 0; k < 8; k++) {          // e0 = sin(ch 4k); masked positions are 0 -> sin = 0
        pA[k] = sinf(hp[(size_t)(4 * k) * AW + eA]);
        pB[k] = sinf(hp[(size_t)(4 * k) * AW + eB]);
    }
    {
        const float* rpA = rowsum + (bc * NA + aA) * 8;
        const float* rpB = rowsum + (bc * NA + aB) * 8;
        const float* cpA = colsum + (bc * NW + wA) * 8;
        const float* cpB = colsum + (bc * NW + wB) * 8;
        #pragma unroll
        for (int k = 0; k < 8; k++) {
            pA[8 + k]  = rpA[k]; pB[8 + k]  = rpB[k];
            pA[16 + k] = cpA[k]; pB[16 + k] = cpB[k];
        }
    }
    float oA[NF], oB[NF];
    #pragma unroll
    for (int f = 0; f < NF; f++) { float bb = b2[f]; oA[f] = bb; oB[f] = bb; }

    for (int j = 0; j < NHID; j++) {
        const float* w1r = w1t + j * 24;   // uniform address -> s_load
        float vA = sconst[j], vB = vA;
        #pragma unroll
        for (int t = 0; t < 24; t++) {
            float q = w1r[t];
            vA = fmaf(pA[t], q, vA);
            vB = fmaf(pB[t], q, vB);
        }
        vA = fmaxf(vA, 0.f); vB = fmaxf(vB, 0.f);
        const float* w2r = w2 + j * NF;    // uniform address -> s_load
        #pragma unroll
        for (int f = 0; f < NF; f++) {
            float q = w2r[f];
            oA[f] = fmaf(vA, q, oA[f]);
            oB[f] = fmaf(vB, q, oB[f]);
        }
    }
    #pragma unroll
    for (int f = 0; f < NF; f++) {         // residual read-modify-write (hv not held across loop)
        float* addr = hp + (size_t)f * AW;
        float rA = addr[eA], rB = addr[eB];
        addr[eA] = (rA + oA[f]) * mkA;
        addr[eB] = (rB + oB[f]) * mkB;
    }
}

// ---------------------------------------------------------------- RMS over (a,w)
__global__ __launch_bounds__(256) void rms_kernel(
    const float* __restrict__ h, const int* __restrict__ rows_len,
    const int* __restrict__ cols_len, float* __restrict__ rms)
{
    int bc = blockIdx.x;
    int f = threadIdx.x >> 3, g = threadIdx.x & 7;
    const float* p = h + ((size_t)bc * NF + f) * AW;
    float s = 0.f;
    for (int i = g; i < AW; i += 8) { float v = p[i]; s = fmaf(v, v, s); }
    __shared__ float red[NF][9];
    red[f][g] = s;
    __syncthreads();
    if (threadIdx.x < NF) {
        float t = 0.f;
        #pragma unroll
        for (int g2 = 0; g2 < 8; g2++) t += red[threadIdx.x][g2];
        float n = (float)(rows_len[bc] * cols_len[bc]);
        t = fmaxf(t, 1e-20f);
        rms[bc * NF + threadIdx.x] = sqrtf(t / fmaxf(n, 1e-12f));
    }
}

// ---------------------------------------------------------------- final mean-over-C + MLP + tanh
__global__ __launch_bounds__(64) void out_kernel(
    const float* __restrict__ rms, const float* __restrict__ w1,
    const float* __restrict__ b1, const float* __restrict__ w2,
    const float* __restrict__ b2, float* __restrict__ out)
{
    int b = threadIdx.x;
    if (b >= NB) return;
    float hm[NF];
    #pragma unroll
    for (int f = 0; f < NF; f++) {
        float s = 0.f;
        for (int c = 0; c < NC; c++) s += rms[(b * NC + c) * NF + f];
        hm[f] = s / (float)NC;
    }
    float o0 = b2[0], o1 = b2[1];
    for (int j = 0; j < NHID; j++) {
        float v = b1[j];
        #pragma unroll
        for (int f = 0; f < NF; f++) v = fmaf(hm[f], w1[f * NHID + j], v);
        v = fmaxf(v, 0.f);
        o0 = fmaf(v, w2[j * 2 + 0], o0);
        o1 = fmaf(v, w2[j * 2 + 1], o1);
    }
    out[b * 2 + 0] = 8.f * tanhf(o0);
    out[b * 2 + 1] = 8.f * tanhf(o1);
}

// ---------------------------------------------------------------- launcher
extern "C" void kernel_launch(void* const* d_in, const int* in_sizes, int n_in,
                              void* d_out, int out_size, void* d_ws, size_t ws_size,
                              hipStream_t stream)
{
    const float* x    = (const float*)d_in[0];
    const int* rl     = (const int*)d_in[1];
    const int* cl     = (const int*)d_in[2];
    const float* t0w1 = (const float*)d_in[3];
    const float* t0b1 = (const float*)d_in[4];
    const float* t0w2 = (const float*)d_in[5];
    const float* t0b2 = (const float*)d_in[6];
    const float* tw1  = (const float*)d_in[7];
    const float* tb1  = (const float*)d_in[8];
    const float* tw2  = (const float*)d_in[9];
    const float* tb2  = (const float*)d_in[10];
    const float* ow1  = (const float*)d_in[11];
    const float* ob1  = (const float*)d_in[12];
    const float* ow2  = (const float*)d_in[13];
    const float* ob2  = (const float*)d_in[14];
    float* out = (float*)d_out;

    float* ws    = (float*)d_ws;
    float* h     = ws;                               // NEL*NF  (planar [bc][f][a*96+w])
    float* stats = h + NEL * NF;                     // 2*NBC
    float* rowb  = stats + 2 * NBC;                  // NBC*NA*8
    float* colb  = rowb + (size_t)NBC * NA * 8;      // NBC*NW*8
    float* matb  = colb + (size_t)NBC * NW * 8;      // NBC*8
    float* cmxb  = matb + NBC * 8;                   // NBC*NF
    float* rmsb  = cmxb + NBC * NF;                  // NBC*NF
    float* w1tb  = rmsb + NBC * NF;                  // 4*NHID*24

    stats_kernel<<<NBC, 256, 0, stream>>>(x, rl, cl, stats);
    prep_kernel<<<(4 * NHID * 24 + 255) / 256, 256, 0, stream>>>(tw1, w1tb);
    t0_kernel<<<(int)(NEL / 512), 256, 0, stream>>>(x, rl, cl, stats,
                                                    t0w1, t0b1, t0w2, t0b2, h);
    for (int s = 0; s < 4; s++) {
        pool_kernel<<<NBC * NF, 256, 0, stream>>>(h, rowb, colb, matb, cmxb);
        mlp_kernel<<<NBC * 18, 256, 0, stream>>>(h, rowb, colb, matb, cmxb, rl, cl,
            w1tb + (size_t)s * NHID * 24,
            tw1 + (size_t)s * 64 * NHID, tb1 + s * NHID,
            tw2 + (size_t)s * NHID * NF, tb2 + s * NF);
    }
    rms_kernel<<<NBC, 256, 0, stream>>>(h, rl, cl, rmsb);
    out_kernel<<<1, 64, 0, stream>>>(rmsb, ow1, ob1, ow2, ob2, out);
}